// Round 2
// baseline (235.561 us; speedup 1.0000x reference)
//
#include <hip/hip_runtime.h>
#include <hip/hip_bf16.h>

#define LSEQ   2048
#define DDIM   1024
#define TI     16
#define TJ     64
#define JOFF   24           // j-window = [i0-24, i0+39]; a^25/(1-a) ~ 3e-9 truncation
#define BK     64
#define NCHUNK (DDIM / BK)  // 16
#define LDST   72           // 64 + 8 pad bf16 elems -> 144B row stride
#define DECAY_F 0.8f

typedef __attribute__((ext_vector_type(8))) short  short8;
typedef __attribute__((ext_vector_type(4))) short  short4v;
typedef __attribute__((ext_vector_type(4))) float  f32x4;

__device__ __forceinline__ unsigned short f2bf(float f) {
  unsigned u = __float_as_uint(f);
  u += 0x7fffu + ((u >> 16) & 1u);
  return (unsigned short)(u >> 16);
}

__global__ __launch_bounds__(256, 4)
void tsp_energy_kernel(const float* __restrict__ x1,
                       const float* __restrict__ x2,
                       float* __restrict__ out) {
  // XCD-aware swizzle: grid=1024, 8 XCDs -> XCD k owns batch k's 128 contiguous
  // i-tiles, so consecutive tiles' 48-row halo overlap stays in that XCD's L2.
  const int bid = blockIdx.x;
  const int wg  = (bid & 7) * 128 + (bid >> 3);
  const int b   = wg >> 7;
  const int i0  = (wg & 127) * TI;
  const int t   = threadIdx.x;
  const int wave = t >> 6;
  const int lane = t & 63;

  __shared__ unsigned short Al[2][TI][LDST];
  __shared__ unsigned short Bl[2][TJ][LDST];
  __shared__ float nsq1p[256], nsq2p[256];
  __shared__ float inv1[TI], inv2[TJ];
  __shared__ float outAcc[TI][4];

  // staging: A 16x64 f32/chunk (4 f32/thread), B 64x64 (16 f32/thread)
  const int arow = t >> 4;
  const int ac0  = (t & 15) * 4;
  const int brow = t >> 2;
  const int bc0  = (t & 3) * 16;
  const int jrow = i0 - JOFF + brow;
  const bool jok = (jrow >= 0) && (jrow < LSEQ);

  const float* ap = x1 + ((size_t)b * LSEQ + (i0 + arow)) * DDIM + ac0;
  const float* bp = jok ? (x2 + ((size_t)b * LSEQ + jrow) * DDIM + bc0) : x2;

  float Ar[2][4], Br[2][16];      // 2-deep reg pipeline (all indices compile-time)
  float nsqa = 0.f, nsqb = 0.f;

  const int l15 = lane & 15;
  const int kof = (lane >> 4) * 8;
  f32x4 acc = (f32x4){0.f, 0.f, 0.f, 0.f};

  auto load_regs = [&](int c, int s) {
    f32x4 a0 = *(const f32x4*)(ap + c * BK);
    #pragma unroll
    for (int j = 0; j < 4; ++j) Ar[s][j] = a0[j];
    if (jok) {
      const float* pb = bp + c * BK;
      #pragma unroll
      for (int q = 0; q < 4; ++q) {
        f32x4 bv = *(const f32x4*)(pb + q * 4);
        #pragma unroll
        for (int j = 0; j < 4; ++j) Br[s][q * 4 + j] = bv[j];
      }
    } else {
      #pragma unroll
      for (int j = 0; j < 16; ++j) Br[s][j] = 0.f;
    }
  };

  auto write_lds = [&](int buf, int s) {
    short4v av;
    #pragma unroll
    for (int j = 0; j < 4; ++j) { float v = Ar[s][j]; nsqa += v * v; av[j] = (short)f2bf(v); }
    *(short4v*)&Al[buf][arow][ac0] = av;
    short8 bv0, bv1;
    #pragma unroll
    for (int j = 0; j < 8; ++j) { float v = Br[s][j];     nsqb += v * v; bv0[j] = (short)f2bf(v); }
    #pragma unroll
    for (int j = 0; j < 8; ++j) { float v = Br[s][8 + j]; nsqb += v * v; bv1[j] = (short)f2bf(v); }
    *(short8*)&Bl[buf][brow][bc0]     = bv0;
    *(short8*)&Bl[buf][brow][bc0 + 8] = bv1;
  };

  auto mfma_step = [&](int buf) {
    short8 af0 = *(const short8*)&Al[buf][l15][kof];
    short8 af1 = *(const short8*)&Al[buf][l15][kof + 32];
    short8 bf0 = *(const short8*)&Bl[buf][wave * 16 + l15][kof];
    short8 bf1 = *(const short8*)&Bl[buf][wave * 16 + l15][kof + 32];
    acc = __builtin_amdgcn_mfma_f32_16x16x32_bf16(af0, bf0, acc, 0, 0, 0);
    acc = __builtin_amdgcn_mfma_f32_16x16x32_bf16(af1, bf1, acc, 0, 0, 0);
  };

  // ---- prologue: chunk0 staged, chunk1 in flight ----
  load_regs(0, 0);
  write_lds(0, 0);
  load_regs(1, 1);
  __syncthreads();

  // ---- main loop: load c+2 early; write c+1 after a full iteration of slack ----
  #pragma unroll
  for (int c = 0; c < NCHUNK; ++c) {
    if (c + 2 < NCHUNK) load_regs(c + 2, c & 1);
    mfma_step(c & 1);
    if (c + 1 < NCHUNK) {
      write_lds((c + 1) & 1, (c + 1) & 1);
      __syncthreads();
    }
  }

  // ---- norms (fp32, accumulated during staging) ----
  nsq1p[t] = nsqa;
  nsq2p[t] = nsqb;
  __syncthreads();
  if (t < TI) {
    float s = 0.f;
    #pragma unroll
    for (int k = 0; k < 16; ++k) s += nsq1p[t * 16 + k];
    inv1[t] = 1.f / fmaxf(sqrtf(s), 1e-8f);
  } else if (t < TI + TJ) {
    int r = t - TI;
    float s = 0.f;
    #pragma unroll
    for (int k = 0; k < 4; ++k) s += nsq2p[r * 4 + k];
    inv2[r] = 1.f / fmaxf(sqrtf(s), 1e-8f);
  }
  __syncthreads();

  // ---- epilogue: weight, normalize (x2 side), reduce over 64 columns ----
  const int jloc = wave * 16 + l15;       // col in window
  const int jrel = jloc - JOFF;           // j - i0
  const float iv2 = inv2[jloc];
  float rowsum[4];
  #pragma unroll
  for (int r = 0; r < 4; ++r) {
    int irel = (lane >> 4) * 4 + r;       // row in tile
    float d = fabsf((float)(jrel - irel));
    rowsum[r] = __expf(-DECAY_F * d) * iv2 * acc[r];
  }
  #pragma unroll
  for (int m = 1; m <= 8; m <<= 1) {
    #pragma unroll
    for (int r = 0; r < 4; ++r) rowsum[r] += __shfl_xor(rowsum[r], m, 64);
  }
  if (l15 == 0) {
    #pragma unroll
    for (int r = 0; r < 4; ++r) outAcc[(lane >> 4) * 4 + r][wave] = rowsum[r];
  }
  __syncthreads();

  if (t < TI) {
    const int i  = i0 + t;
    const float A  = __expf(-DECAY_F);
    const float a1 = __expf(-DECAY_F * (float)(i + 1));
    const float a2 = __expf(-DECAY_F * (float)(LSEQ - i));
    const float Wi = (1.f - a1 + A - a2) / (1.f - A);   // exact sum_j a^|i-j|
    out[(size_t)b * LSEQ + i] =
        Wi - inv1[t] * (outAcc[t][0] + outAcc[t][1] + outAcc[t][2] + outAcc[t][3]);
  }
}

extern "C" void kernel_launch(void* const* d_in, const int* in_sizes, int n_in,
                              void* d_out, int out_size, void* d_ws, size_t ws_size,
                              hipStream_t stream) {
  const float* x1 = (const float*)d_in[0];
  const float* x2 = (const float*)d_in[1];
  float* out = (float*)d_out;
  dim3 grid(8 * (LSEQ / TI));   // 1024 WGs = 4 per CU
  dim3 block(256);
  tsp_energy_kernel<<<grid, block, 0, stream>>>(x1, x2, out);
}

// Round 3
// 45.647 us; speedup vs baseline: 5.1606x; 5.1606x over previous
//
#include <hip/hip_runtime.h>

#define LSEQ   2048
#define DDIM   1024
#define BR     32          // rows per WG (same row range for x1 and x2)
#define BK     64
#define NCH    (DDIM/BK)   // 16 K-chunks
#define LDST   72          // 64 + 8 pad bf16 elems -> 144B row stride
#define WPB    127         // WGs per batch: 64 diagonal + 63 offset
#define DECAY_F 0.8f

typedef __attribute__((ext_vector_type(8))) short  short8;
typedef __attribute__((ext_vector_type(4))) float  f32x4;

__device__ __forceinline__ unsigned short f2bf(float f) {
  unsigned u = __float_as_uint(f);
  u += 0x7fffu + ((u >> 16) & 1u);
  return (unsigned short)(u >> 16);
}

__device__ __forceinline__ void cvt_store(unsigned short* dst, f32x4 lo, f32x4 hi, float& nsq) {
  short8 v;
  #pragma unroll
  for (int j = 0; j < 4; ++j) { float x = lo[j]; nsq += x * x; v[j]     = (short)f2bf(x); }
  #pragma unroll
  for (int j = 0; j < 4; ++j) { float x = hi[j]; nsq += x * x; v[4 + j] = (short)f2bf(x); }
  *(short8*)dst = v;
}

__global__ __launch_bounds__(256, 4)
void tsp_energy_kernel(const float* __restrict__ x1,
                       const float* __restrict__ x2,
                       float* __restrict__ out) {
  // grid = 1016 = 8*127 exactly: bid&7 = XCD = batch, bid>>3 = WG within batch.
  // Consecutive in-batch WGs (D_k, O_k share 16 rows) stay on one XCD's L2.
  const int bid  = blockIdx.x;
  const int b    = bid & 7;
  const int r    = bid >> 3;           // 0..126
  const bool isO = (r >= 64);
  const int row0 = isO ? ((r - 64) * BR + 16) : (r * BR);  // O rows straddle a 32-boundary at local 16

  const int t    = threadIdx.x;
  const int lane = t & 63;
  const int wave = t >> 6;             // 4 waves
  const int l15  = lane & 15;
  const int g4   = lane >> 4;
  const int mrow = (wave >> 1) * 16;   // wave -> 16x16 out tile
  const int ncol = (wave & 1) * 16;

  __shared__ unsigned short Al[2][BR][LDST];
  __shared__ unsigned short Bl[2][BR][LDST];
  __shared__ float nsq1p[256], nsq2p[256];
  __shared__ float inv1s[BR], inv2s[BR];
  __shared__ float outAcc[BR][2];

  // staging: each thread owns row t>>3, cols (t&7)*8 .. +7 of each 32x64 chunk
  const int srow = t >> 3;
  const int scol = (t & 7) * 8;
  const float* ap = x1 + ((size_t)b * LSEQ + row0 + srow) * DDIM + scol;
  const float* bp = x2 + ((size_t)b * LSEQ + row0 + srow) * DDIM + scol;
  unsigned short* la = &Al[0][srow][scol];   // buf stride in elems:
  unsigned short* lb = &Bl[0][srow][scol];
  const int BUFE = BR * LDST;                // elems per buffer

  float nsqa = 0.f, nsqb = 0.f;
  f32x4 acc = (f32x4){0.f, 0.f, 0.f, 0.f};

  // named 2-slot register pipeline — NO runtime-indexed arrays (scratch trap)
  f32x4 a0l, a0h, b0l, b0h, a1l, a1h, b1l, b1h;

#define LOAD0(off) do { a0l = *(const f32x4*)(ap + (off));     a0h = *(const f32x4*)(ap + (off) + 4); \
                        b0l = *(const f32x4*)(bp + (off));     b0h = *(const f32x4*)(bp + (off) + 4); } while (0)
#define LOAD1(off) do { a1l = *(const f32x4*)(ap + (off));     a1h = *(const f32x4*)(ap + (off) + 4); \
                        b1l = *(const f32x4*)(bp + (off));     b1h = *(const f32x4*)(bp + (off) + 4); } while (0)
#define WLDS0(buf) do { cvt_store(la + (buf) * BUFE, a0l, a0h, nsqa); \
                        cvt_store(lb + (buf) * BUFE, b0l, b0h, nsqb); } while (0)
#define WLDS1(buf) do { cvt_store(la + (buf) * BUFE, a1l, a1h, nsqa); \
                        cvt_store(lb + (buf) * BUFE, b1l, b1h, nsqb); } while (0)

  auto mstep = [&](int buf) {
    const unsigned short* pa = &Al[buf][mrow + l15][g4 * 8];
    const unsigned short* pb = &Bl[buf][ncol + l15][g4 * 8];
    short8 af0 = *(const short8*)pa;
    short8 bf0 = *(const short8*)pb;
    short8 af1 = *(const short8*)(pa + 32);
    short8 bf1 = *(const short8*)(pb + 32);
    acc = __builtin_amdgcn_mfma_f32_16x16x32_bf16(af0, bf0, acc, 0, 0, 0);
    acc = __builtin_amdgcn_mfma_f32_16x16x32_bf16(af1, bf1, acc, 0, 0, 0);
  };

  // ---- prologue: chunk0 -> buf0, chunk1 in regs ----
  LOAD0(0);
  WLDS0(0);
  LOAD1(BK);
  __syncthreads();                       // buf0 ready

  // ---- main loop: 2 chunks / iter, 2 barriers / iter, 2-deep reg prefetch ----
  #pragma unroll
  for (int it = 0; it < 7; ++it) {
    const int off = it * 2 * BK;
    LOAD0(off + 2 * BK);                 // chunk e+2 -> slot0 (old slot0 already in LDS)
    mstep(0);                            // consume buf0 (chunk e)
    WLDS1(1);                            // chunk e+1 -> buf1
    __syncthreads();                     // buf1 ready; buf0 reads drained
    LOAD1(off + 3 * BK);                 // chunk e+3 -> slot1
    mstep(1);                            // consume buf1
    WLDS0(0);                            // chunk e+2 -> buf0
    __syncthreads();                     // buf0 ready
  }
  // chunks 14 (buf0) and 15 (slot1) remain
  mstep(0);
  WLDS1(1);
  __syncthreads();
  mstep(1);

  // ---- norms (fp32, accumulated during cvt) ----
  nsq1p[t] = nsqa;
  nsq2p[t] = nsqb;
  __syncthreads();
  if (t < BR) {
    float s = 0.f;
    #pragma unroll
    for (int k = 0; k < 8; ++k) s += nsq1p[t * 8 + k];
    inv1s[t] = 1.f / fmaxf(sqrtf(s), 1e-8f);
  } else if (t < 2 * BR) {
    const int rr = t - BR;
    float s = 0.f;
    #pragma unroll
    for (int k = 0; k < 8; ++k) s += nsq2p[rr * 8 + k];
    inv2s[rr] = 1.f / fmaxf(sqrtf(s), 1e-8f);
  }
  __syncthreads();

  // ---- epilogue: weight (+O parity mask), normalize, reduce over 32 cols ----
  const int jc = ncol + l15;             // local col
  const float iv2 = inv2s[jc];
  float rs[4];
  #pragma unroll
  for (int q = 0; q < 4; ++q) {
    const int ic = mrow + g4 * 4 + q;    // local row
    float w = __expf(-DECAY_F * fabsf((float)(ic - jc)));
    if (isO && ((ic < 16) == (jc < 16))) w = 0.f;  // O: cross-boundary pairs only
    rs[q] = w * iv2 * acc[q];
  }
  #pragma unroll
  for (int m = 1; m <= 8; m <<= 1) {
    #pragma unroll
    for (int q = 0; q < 4; ++q) rs[q] += __shfl_xor(rs[q], m, 64);
  }
  if (l15 == 0) {
    #pragma unroll
    for (int q = 0; q < 4; ++q) outAcc[mrow + g4 * 4 + q][wave & 1] = rs[q];
  }
  __syncthreads();

  if (t < BR) {
    const float v = inv1s[t] * (outAcc[t][0] + outAcc[t][1]);
    const int gi = row0 + t;
    float res;
    if (isO) {
      res = -v;
    } else {
      const float A  = __expf(-DECAY_F);
      const float a1 = __expf(-DECAY_F * (float)(gi + 1));
      const float a2 = __expf(-DECAY_F * (float)(LSEQ - gi));
      res = (1.f - a1 + A - a2) / (1.f - A) - v;   // exact sum_j a^|i-j|
    }
    atomicAdd(out + (size_t)b * LSEQ + gi, res);
  }
}

extern "C" void kernel_launch(void* const* d_in, const int* in_sizes, int n_in,
                              void* d_out, int out_size, void* d_ws, size_t ws_size,
                              hipStream_t stream) {
  const float* x1 = (const float*)d_in[0];
  const float* x2 = (const float*)d_in[1];
  float* out = (float*)d_out;
  hipMemsetAsync(d_out, 0, (size_t)out_size * sizeof(float), stream);
  dim3 grid(8 * WPB);   // 1016 WGs ~= 4 per CU
  dim3 block(256);
  tsp_energy_kernel<<<grid, block, 0, stream>>>(x1, x2, out);
}